// Round 11
// baseline (729.701 us; speedup 1.0000x reference)
//
#include <hip/hip_runtime.h>

using u16 = unsigned short;

typedef __bf16 bf16x8 __attribute__((ext_vector_type(8)));
typedef u16    u16x8  __attribute__((ext_vector_type(8)));
typedef float  f32x4  __attribute__((ext_vector_type(4)));

__device__ __forceinline__ float b2f(u16 u) {
    union { unsigned int i; float f; } c; c.i = ((unsigned int)u) << 16; return c.f;
}
__device__ __forceinline__ u16 f2b(float f) {
    union { float f; unsigned int i; } c; c.f = f;
    unsigned int i = c.i;
    return (u16)((i + 0x7FFFu + ((i >> 16) & 1u)) >> 16);
}
__device__ __forceinline__ unsigned cvtpk(float lo, float hi) {
    unsigned d;
    asm("v_cvt_pk_bf16_f32 %0, %1, %2" : "=v"(d) : "v"(lo), "v"(hi));
    return d;
}

#define AS1 __attribute__((address_space(1)))
#define AS3 __attribute__((address_space(3)))
__device__ __forceinline__ void glds16(const u16* g, u16* l) {
    __builtin_amdgcn_global_load_lds((const AS1 void*)(const void*)g,
                                     (AS3 void*)(void*)l, 16, 0, 0);
}

// ---------------------------------------------------------------------------
// Batched transpose + convert f32 -> bf16: in[b][R][C] f32 -> out[b][C][R] bf16
// ---------------------------------------------------------------------------
__global__ void btrans_f2b(const float* __restrict__ in, u16* __restrict__ out, int R, int C) {
    __shared__ u16 tile[32][33];
    const int c0 = blockIdx.x * 32, r0 = blockIdx.y * 32;
    const size_t base = (size_t)blockIdx.z * R * C;
    const int tx = threadIdx.x, ty = threadIdx.y;
    #pragma unroll
    for (int i = ty; i < 32; i += 8) {
        int r = r0 + i, c = c0 + tx;
        tile[i][tx] = (r < R && c < C) ? f2b(in[base + (size_t)r * C + c]) : (u16)0;
    }
    __syncthreads();
    #pragma unroll
    for (int i = ty; i < 32; i += 8) {
        int c = c0 + i, r = r0 + tx;
        if (c < C && r < R) out[base + (size_t)c * R + r] = tile[tx][i];
    }
}

// Batched transpose + convert bf16 -> f32: in[b][R][C] bf16 -> out[b][C][R] f32
__global__ void btrans_b2f(const u16* __restrict__ in, float* __restrict__ out, int R, int C) {
    __shared__ u16 tile[32][33];
    const int c0 = blockIdx.x * 32, r0 = blockIdx.y * 32;
    const size_t base = (size_t)blockIdx.z * R * C;
    const int tx = threadIdx.x, ty = threadIdx.y;
    #pragma unroll
    for (int i = ty; i < 32; i += 8) {
        int r = r0 + i, c = c0 + tx;
        tile[i][tx] = (r < R && c < C) ? in[base + (size_t)r * C + c] : (u16)0;
    }
    __syncthreads();
    #pragma unroll
    for (int i = ty; i < 32; i += 8) {
        int c = c0 + i, r = r0 + tx;
        if (c < C && r < R) out[base + (size_t)c * R + r] = b2f(tile[tx][i]);
    }
}

// ---------------------------------------------------------------------------
// GEMM: C[M,N] = epilogue(A[M,K] @ BT[N,K]^T + bias)   (A,BT,C bf16)
// R13: 128x128 block tile, BK=64 (was 32), 8 waves (2M x 4N), 64x32 per-wave.
// Rationale: six structural experiments all land at 424-470 TF; the constant
// is BK=32's ~600cy barrier-drain per ~300cy of compute. BK=64 halves the
// number of drains at constant residency: LDS 64 KB (A 2x16K, B 2x16K) still
// fits 2 blocks/CU; per K-step/wave = 16 MFMA + 12 ds_read_b128 + 4 glds
// against ONE drain. Layout = proven [kc][rows][32] chunk scheme (0 conflicts
// measured). Sync skeleton unchanged (2-buffer, one __syncthreads per step).
// Epilogue: cross-lane pair-pack + dword stores. EPI=1 residual restaged
// through LDS in one 32 KB pass. XCD-aware bijective block swizzle.
// EPI: 0 = bias only; 1 = bias+residual+RepBN; 2 = bias+SpatialSiLU
// ---------------------------------------------------------------------------
template<int EPI>
__launch_bounds__(512, 4)
__global__ void gemm_bt(const u16* __restrict__ A, const u16* __restrict__ BT,
                        const float* __restrict__ bias, u16* __restrict__ C,
                        int M, int N, int K, int row0,
                        const u16* __restrict__ R0,
                        const float* __restrict__ g, const float* __restrict__ be,
                        const float* __restrict__ rmv, const float* __restrict__ rvv,
                        const float* __restrict__ alpha,
                        const float* __restrict__ saw, const float* __restrict__ sab) {
    // A: [0, 16384) = 2 bufs x 8192 ([kc][128 rows][32]); B: [16384, 32768) same
    __shared__ __align__(16) u16 SL[32768];  // 64 KB
    const int tid  = threadIdx.x;
    const int wave = tid >> 6, lane = tid & 63;
    const int wm = wave >> 2, wn = wave & 3;      // 2M x 4N wave grid
    const int quad = lane >> 4, l16 = lane & 15;

    // XCD-aware bijective block swizzle (m204)
    const unsigned gx = gridDim.x;
    unsigned lin = blockIdx.y * gx + blockIdx.x;
    const unsigned nwg = gx * gridDim.y;
    const unsigned q8 = nwg >> 3, r8 = nwg & 7;
    const unsigned xcd = lin & 7, loc = lin >> 3;
    lin = (xcd < r8 ? xcd * (q8 + 1) : r8 * (q8 + 1) + (xcd - r8) * q8) + loc;
    const int m0 = (int)(lin / gx) * 128, n0 = (int)(lin % gx) * 128;

    // staging: wave stages its 16 rows of A and of B, 2 k-chunks each (4 glds).
    const int srow = lane >> 2;                                   // 0..15
    const int scol = (((lane & 3) ^ ((srow >> 1) & 3)) * 8);      // swizzled source chunk
    const size_t aoff = (size_t)(m0 + wave * 16 + srow) * K + scol;
    const size_t boff = (size_t)(n0 + wave * 16 + srow) * K + scol;

    // fragment read column (undo swizzle): global chunk = quad
    const int cfrag = (quad ^ ((l16 >> 1) & 3)) * 8;

    f32x4 acc[4][2] = {};
    const int niter = K >> 6;

    auto stage = [&](int buf, size_t kn) {
        #pragma unroll
        for (int kc = 0; kc < 2; kc++) {
            glds16(A  + aoff + kn + kc * 32, SL + buf * 8192 + kc * 4096 + wave * 512);
            glds16(BT + boff + kn + kc * 32, SL + 16384 + buf * 8192 + kc * 4096 + wave * 512);
        }
    };

    auto kstep = [&](int cur, int kt) {
        __syncthreads();  // drains vmcnt(0): buf[cur] ready; buf[cur^1] readers done
        if (kt + 1 < niter) stage(cur ^ 1, (size_t)(kt + 1) << 6);
        const u16* ab = SL + cur * 8192;
        const u16* bb = SL + 16384 + cur * 8192;
        #pragma unroll
        for (int kk = 0; kk < 2; kk++) {
            bf16x8 af[4], bfr[2];
            #pragma unroll
            for (int i = 0; i < 4; i++)
                af[i] = *(const bf16x8*)&ab[kk * 4096 + (wm * 64 + i * 16 + l16) * 32 + cfrag];
            #pragma unroll
            for (int j = 0; j < 2; j++)
                bfr[j] = *(const bf16x8*)&bb[kk * 4096 + (wn * 32 + j * 16 + l16) * 32 + cfrag];
            #pragma unroll
            for (int i = 0; i < 4; i++)
                #pragma unroll
                for (int j = 0; j < 2; j++)
                    acc[i][j] = __builtin_amdgcn_mfma_f32_16x16x32_bf16(af[i], bfr[j], acc[i][j], 0, 0, 0);
        }
    };

    // prologue: issue tile 0 into buffer 0
    stage(0, 0);
    int kt = 0;
    for (; kt + 2 <= niter; kt += 2) { kstep(0, kt); kstep(1, kt + 1); }
    if (kt < niter) kstep(kt & 1, kt);

    // ---------------- epilogue ----------------
    __syncthreads();  // all K-loop LDS reads done before any reuse of SL

    float alphav = 0.f;
    if (EPI == 1) alphav = alpha[0];

    if (EPI == 1) {
        // residual tile [128][128] restaged into SL (one 32 KB pass)
        for (int c = tid; c < 2048; c += 512) {
            int row = c >> 4, colc = (c & 15) * 8;
            *(u16x8*)&SL[row * 128 + colc] =
                *(const u16x8*)&R0[(size_t)(m0 + row) * N + n0 + colc];
        }
        __syncthreads();
    }

    // per-column (j) constants
    float biasv[2], k0p[2][2], k1p[2][2];
    const int dup = l16 & 1;            // which row-pair this lane stores
    const int pr  = l16 >> 1;           // column pair index (0..7)
    #pragma unroll
    for (int j = 0; j < 2; j++) {
        biasv[j] = bias[n0 + wn * 32 + j * 16 + l16];
        if (EPI == 1) {
            #pragma unroll
            for (int p = 0; p < 2; p++) {
                const int col = n0 + wn * 32 + j * 16 + pr * 2 + p;
                const float sc = g[col] * rsqrtf(rvv[col] + 1e-5f);
                k1p[j][p] = sc + alphav;
                k0p[j][p] = be[col] - rmv[col] * sc;
            }
        }
    }

    u16* Crow = C + (size_t)(m0 + wm * 64 + quad * 4 + 2 * dup) * N
                  + (n0 + wn * 32 + pr * 2);
    const int r0i = 2 * dup, r1i = r0i + 1;

    #pragma unroll
    for (int i = 0; i < 4; i++) {
        float swv4[4], sbv4[4];
        if (EPI == 2) {
            #pragma unroll
            for (int r = 0; r < 4; r++) {
                const int row = row0 + m0 + wm * 64 + i * 16 + quad * 4 + r;
                const int bidx = row / 196;
                swv4[r] = saw[bidx]; sbv4[r] = sab[bidx];
            }
        }
        #pragma unroll
        for (int j = 0; j < 2; j++) {
            float vv[4];
            #pragma unroll
            for (int r = 0; r < 4; r++) {
                float v = acc[i][j][r] + biasv[j];
                if (EPI == 2) {
                    float w = fmaf(swv4[r], v, sbv4[r]);
                    v = v / (1.f + __expf(-w * v));
                }
                vv[r] = v;
            }
            float ot[4];
            #pragma unroll
            for (int r = 0; r < 4; r++) ot[r] = __shfl_xor(vv[r], 1, 64);
            float lo0 = dup ? ot[r0i] : vv[r0i], hi0 = dup ? vv[r0i] : ot[r0i];
            float lo1 = dup ? ot[r1i] : vv[r1i], hi1 = dup ? vv[r1i] : ot[r1i];
            if (EPI == 1) {
                const int rowL = wm * 64 + i * 16 + quad * 4 + r0i;
                const int colp = wn * 32 + j * 16 + pr * 2;
                const unsigned rd0 = *(const unsigned*)&SL[rowL * 128 + colp];
                const unsigned rd1 = *(const unsigned*)&SL[(rowL + 1) * 128 + colp];
                lo0 = fmaf(lo0 + b2f((u16)(rd0 & 0xffff)), k1p[j][0], k0p[j][0]);
                hi0 = fmaf(hi0 + b2f((u16)(rd0 >> 16)),    k1p[j][1], k0p[j][1]);
                lo1 = fmaf(lo1 + b2f((u16)(rd1 & 0xffff)), k1p[j][0], k0p[j][0]);
                hi1 = fmaf(hi1 + b2f((u16)(rd1 >> 16)),    k1p[j][1], k0p[j][1]);
            }
            u16* p = Crow + (size_t)i * 16 * N + j * 16;
            *(unsigned*)p       = cvtpk(lo0, hi0);
            *(unsigned*)(p + N) = cvtpk(lo1, hi1);
        }
    }
}

// ---------------------------------------------------------------------------
// MFMA flash attention: one block per (local b, h), 4 waves.
// V staging vectorized (u16x8 row reads + scalar transposed LDS writes).
// ---------------------------------------------------------------------------
__launch_bounds__(256)
__global__ void attn_kernel(const u16* __restrict__ qkv, u16* __restrict__ o) {
    __shared__ __align__(16) u16 Kb[224 * 32];
    __shared__ __align__(16) u16 Vt[32 * 232];
    __shared__ __align__(16) u16 Pl[4][16 * 232];
    const int tid  = threadIdx.x;
    const int wave = tid >> 6, lane = tid & 63;
    const int quad = lane >> 4, l16 = lane & 15;
    const int b = blockIdx.x >> 3, h = blockIdx.x & 7;
    const u16* qg = qkv + (size_t)b * 196 * 768 + h * 32;
    const float scale = 0.17677669529663687f; // 1/sqrt(32)

    for (int idx = tid; idx < 896; idx += 256) {
        int row = idx >> 2, dp = (idx & 3) * 8;
        u16x8 kv = {};
        if (row < 196) kv = *(const u16x8*)&qg[(size_t)row * 768 + 256 + dp];
        *(u16x8*)&Kb[row * 32 + dp] = kv;
    }
    for (int idx = tid; idx < 896; idx += 256) {
        int row = idx >> 2, dp = (idx & 3) * 8;
        u16x8 vv = {};
        if (row < 196) vv = *(const u16x8*)&qg[(size_t)row * 768 + 512 + dp];
        #pragma unroll
        for (int e = 0; e < 8; e++) Vt[(dp + e) * 232 + row] = vv[e];
    }
    for (int c = lane; c < 16 * 24; c += 64) {
        int m = c / 24, cc = 208 + (c % 24);
        Pl[wave][m * 232 + cc] = 0;
    }
    __syncthreads();

    for (int t = wave; t < 13; t += 4) {
        const int m0 = t * 16;
        bf16x8 aq = {};
        const int qrow = m0 + l16;
        if (qrow < 196) aq = *(const bf16x8*)&qg[(size_t)qrow * 768 + quad * 8];

        f32x4 s[13];
        #pragma unroll
        for (int ct = 0; ct < 13; ct++) {
            bf16x8 bk = *(const bf16x8*)&Kb[(ct * 16 + l16) * 32 + quad * 8];
            s[ct] = __builtin_amdgcn_mfma_f32_16x16x32_bf16(aq, bk, (f32x4){0.f, 0.f, 0.f, 0.f}, 0, 0, 0);
        }
        if (l16 >= 4) {
            #pragma unroll
            for (int r = 0; r < 4; r++) s[12][r] = -1e30f;
        }
        float mx[4] = {-1e30f, -1e30f, -1e30f, -1e30f};
        #pragma unroll
        for (int ct = 0; ct < 13; ct++)
            #pragma unroll
            for (int r = 0; r < 4; r++) mx[r] = fmaxf(mx[r], s[ct][r]);
        #pragma unroll
        for (int off = 1; off < 16; off <<= 1)
            #pragma unroll
            for (int r = 0; r < 4; r++) mx[r] = fmaxf(mx[r], __shfl_xor(mx[r], off, 64));
        float sum[4] = {0.f, 0.f, 0.f, 0.f};
        #pragma unroll
        for (int ct = 0; ct < 13; ct++) {
            #pragma unroll
            for (int r = 0; r < 4; r++) {
                float p = __expf((s[ct][r] - mx[r]) * scale);
                sum[r] += p;
                Pl[wave][(quad * 4 + r) * 232 + ct * 16 + l16] = f2b(p);
            }
        }
        #pragma unroll
        for (int off = 1; off < 16; off <<= 1)
            #pragma unroll
            for (int r = 0; r < 4; r++) sum[r] += __shfl_xor(sum[r], off, 64);
        float inv[4];
        #pragma unroll
        for (int r = 0; r < 4; r++) inv[r] = 1.f / sum[r];

        #pragma unroll
        for (int nt = 0; nt < 2; nt++) {
            f32x4 ao = {0.f, 0.f, 0.f, 0.f};
            #pragma unroll
            for (int kc = 0; kc < 7; kc++) {
                bf16x8 ap = *(const bf16x8*)&Pl[wave][l16 * 232 + kc * 32 + quad * 8];
                bf16x8 bv = *(const bf16x8*)&Vt[(nt * 16 + l16) * 232 + kc * 32 + quad * 8];
                ao = __builtin_amdgcn_mfma_f32_16x16x32_bf16(ap, bv, ao, 0, 0, 0);
            }
            #pragma unroll
            for (int r = 0; r < 4; r++) {
                const int gm = m0 + quad * 4 + r;
                if (gm < 196)
                    o[((size_t)b * 196 + gm) * 256 + h * 32 + nt * 16 + l16] = f2b(ao[r] * inv[r]);
            }
        }
    }
}

// ---------------------------------------------------------------------------
extern "C" void kernel_launch(void* const* d_in, const int* in_sizes, int n_in,
                              void* d_out, int out_size, void* d_ws, size_t ws_size,
                              hipStream_t stream) {
    const float* x      = (const float*)d_in[0];
    const float* Wqkv   = (const float*)d_in[1];
    const float* bqkv   = (const float*)d_in[2];
    const float* Wproj  = (const float*)d_in[3];
    const float* bproj  = (const float*)d_in[4];
    const float* W1     = (const float*)d_in[5];
    const float* b1     = (const float*)d_in[6];
    const float* W2     = (const float*)d_in[7];
    const float* b2     = (const float*)d_in[8];
    const float* saw    = (const float*)d_in[9];
    const float* sab    = (const float*)d_in[10];
    const float* alpha1 = (const float*)d_in[11];
    const float* g1     = (const float*)d_in[12];
    const float* be1    = (const float*)d_in[13];
    const float* rm1    = (const float*)d_in[14];
    const float* rv1    = (const float*)d_in[15];
    const float* alpha2 = (const float*)d_in[16];
    const float* g2     = (const float*)d_in[17];
    const float* be2    = (const float*)d_in[18];
    const float* rm2    = (const float*)d_in[19];
    const float* rv2    = (const float*)d_in[20];

    const int B = 256, Cc = 256, Np = 196, CM = 2048;
    const int M = B * Np; // 50176

    auto al = [](size_t s) { return (s + 255) & ~(size_t)255; };
    char* ws = (char*)d_ws;
    const size_t o_t0  = 0;
    const size_t o_t1  = o_t0 + al((size_t)M * Cc * 2);
    const size_t o_wq  = o_t1 + al((size_t)M * Cc * 2);
    const size_t o_wp  = o_wq + al((size_t)768 * Cc * 2);
    const size_t o_w1  = o_wp + al((size_t)Cc * Cc * 2);
    const size_t o_w2  = o_w1 + al((size_t)Cc * CM * 2);
    const size_t o_scr = o_w2 + al((size_t)CM * Cc * 2);
    const size_t S = (ws_size > o_scr) ? ws_size - o_scr : 0;

    u16* t0     = (u16*)(ws + o_t0);
    u16* t1b    = (u16*)(ws + o_t1);
    u16* WqkvT  = (u16*)(ws + o_wq);
    u16* WprojT = (u16*)(ws + o_wp);
    u16* W1T    = (u16*)(ws + o_w1);
    u16* W2T    = (u16*)(ws + o_w2);
    u16* scr    = (u16*)(ws + o_scr);
    u16* t2     = t0;            // alias: t0 dead after proj epilogue
    u16* obuf   = (u16*)d_out;   // bf16 scratch in f32 d_out; fully rewritten by final btrans
    float* out  = (float*)d_out;

    // chunk counts: M-chunks multiples of 128.
    int nq = 1; while (nq < 4 && ((size_t)(M / nq) * 768 * 2) > S) nq *= 2;
    const int nf_opts[7] = {1, 2, 4, 8, 14, 28, 56};
    int nf = 56;
    for (int i = 0; i < 7; ++i) {
        if (((size_t)(M / nf_opts[i]) * CM * 2) <= S) { nf = nf_opts[i]; break; }
    }
    const int Mq = M / nq, Bq = B / nq;
    const int Mf = M / nf;

    dim3 tb(32, 8, 1);
    // x f32 [B][C][N] -> t0 bf16 [B][N][C]
    btrans_f2b<<<dim3((Np + 31) / 32, (Cc + 31) / 32, B), tb, 0, stream>>>(x, t0, Cc, Np);
    // weights f32 [K][N] -> bf16 [N][K]
    btrans_f2b<<<dim3(768 / 32, Cc / 32, 1), tb, 0, stream>>>(Wqkv,  WqkvT,  Cc, 768);
    btrans_f2b<<<dim3(Cc  / 32, Cc / 32, 1), tb, 0, stream>>>(Wproj, WprojT, Cc, Cc);
    btrans_f2b<<<dim3(CM  / 32, Cc / 32, 1), tb, 0, stream>>>(W1,    W1T,    Cc, CM);
    btrans_f2b<<<dim3(Cc  / 32, CM / 32, 1), tb, 0, stream>>>(W2,    W2T,    CM, Cc);

    // qkv + attention, chunked over batches
    for (int c = 0; c < nq; ++c) {
        gemm_bt<0><<<dim3(768 / 128, Mq / 128), 512, 0, stream>>>(
            t0 + (size_t)c * Mq * Cc, WqkvT, bqkv, scr, Mq, 768, Cc, 0,
            nullptr, nullptr, nullptr, nullptr, nullptr, nullptr, nullptr, nullptr);
        attn_kernel<<<dim3(Bq * 8), 256, 0, stream>>>(scr, obuf + (size_t)c * Mq * Cc);
    }

    // t1 = RepBN1(t0 + obuf @ Wproj + bproj)
    gemm_bt<1><<<dim3(Cc / 128, M / 128), 512, 0, stream>>>(
        obuf, WprojT, bproj, t1b, M, Cc, Cc, 0,
        t0, g1, be1, rm1, rv1, alpha1, nullptr, nullptr);

    // FFN, chunked over rows
    for (int c = 0; c < nf; ++c) {
        gemm_bt<2><<<dim3(CM / 128, Mf / 128), 512, 0, stream>>>(
            t1b + (size_t)c * Mf * Cc, W1T, b1, scr, Mf, CM, Cc, c * Mf,
            nullptr, nullptr, nullptr, nullptr, nullptr, nullptr, saw, sab);
        gemm_bt<1><<<dim3(Cc / 128, Mf / 128), 512, 0, stream>>>(
            scr, W2T, b2, t2 + (size_t)c * Mf * Cc, Mf, Cc, CM, 0,
            t1b + (size_t)c * Mf * Cc, g2, be2, rm2, rv2, alpha2, nullptr, nullptr);
    }

    // t2 bf16 [B][N][C] -> out f32 [B][C][N]
    btrans_b2f<<<dim3((Cc + 31) / 32, (Np + 31) / 32, B), tb, 0, stream>>>(t2, out, Np, Cc);
}

// Round 14
// 563.323 us; speedup vs baseline: 1.2954x; 1.2954x over previous
//
#include <hip/hip_runtime.h>

using u16 = unsigned short;

typedef __bf16 bf16x8 __attribute__((ext_vector_type(8)));
typedef u16    u16x8  __attribute__((ext_vector_type(8)));
typedef float  f32x4  __attribute__((ext_vector_type(4)));

__device__ __forceinline__ float b2f(u16 u) {
    union { unsigned int i; float f; } c; c.i = ((unsigned int)u) << 16; return c.f;
}
__device__ __forceinline__ u16 f2b(float f) {
    union { float f; unsigned int i; } c; c.f = f;
    unsigned int i = c.i;
    return (u16)((i + 0x7FFFu + ((i >> 16) & 1u)) >> 16);
}
__device__ __forceinline__ unsigned cvtpk(float lo, float hi) {
    unsigned d;
    asm("v_cvt_pk_bf16_f32 %0, %1, %2" : "=v"(d) : "v"(lo), "v"(hi));
    return d;
}

#define AS1 __attribute__((address_space(1)))
#define AS3 __attribute__((address_space(3)))
__device__ __forceinline__ void glds16(const u16* g, u16* l) {
    __builtin_amdgcn_global_load_lds((const AS1 void*)(const void*)g,
                                     (AS3 void*)(void*)l, 16, 0, 0);
}

// ---------------------------------------------------------------------------
// Batched transpose + convert f32 -> bf16: in[b][R][C] f32 -> out[b][C][R] bf16
// ---------------------------------------------------------------------------
__global__ void btrans_f2b(const float* __restrict__ in, u16* __restrict__ out, int R, int C) {
    __shared__ u16 tile[32][33];
    const int c0 = blockIdx.x * 32, r0 = blockIdx.y * 32;
    const size_t base = (size_t)blockIdx.z * R * C;
    const int tx = threadIdx.x, ty = threadIdx.y;
    #pragma unroll
    for (int i = ty; i < 32; i += 8) {
        int r = r0 + i, c = c0 + tx;
        tile[i][tx] = (r < R && c < C) ? f2b(in[base + (size_t)r * C + c]) : (u16)0;
    }
    __syncthreads();
    #pragma unroll
    for (int i = ty; i < 32; i += 8) {
        int c = c0 + i, r = r0 + tx;
        if (c < C && r < R) out[base + (size_t)c * R + r] = tile[tx][i];
    }
}

// Batched transpose + convert bf16 -> f32: in[b][R][C] bf16 -> out[b][C][R] f32
__global__ void btrans_b2f(const u16* __restrict__ in, float* __restrict__ out, int R, int C) {
    __shared__ u16 tile[32][33];
    const int c0 = blockIdx.x * 32, r0 = blockIdx.y * 32;
    const size_t base = (size_t)blockIdx.z * R * C;
    const int tx = threadIdx.x, ty = threadIdx.y;
    #pragma unroll
    for (int i = ty; i < 32; i += 8) {
        int r = r0 + i, c = c0 + tx;
        tile[i][tx] = (r < R && c < C) ? in[base + (size_t)r * C + c] : (u16)0;
    }
    __syncthreads();
    #pragma unroll
    for (int i = ty; i < 32; i += 8) {
        int c = c0 + i, r = r0 + tx;
        if (c < C && r < R) out[base + (size_t)c * R + r] = b2f(tile[tx][i]);
    }
}

// ---------------------------------------------------------------------------
// GEMM: C[M,N] = epilogue(A[M,K] @ BT[N,K]^T + bias)   (A,BT,C bf16)
// R9/R8 proven (515 us state): 256x128 block tile, BK=32, 8 waves (4M x 2N),
// 64x64 per-wave tiles. 2-buffer, one-__syncthreads-per-K-step skeleton.
// LDS 48 KB (A 2x16K, B 2x8K) -> 3 blocks/CU. Pair-pack epilogue.
// EPI: 0 = bias only; 1 = bias+residual+RepBN; 2 = bias+SpatialSiLU
// ---------------------------------------------------------------------------
template<int EPI>
__launch_bounds__(512, 4)
__global__ void gemm_bt(const u16* __restrict__ A, const u16* __restrict__ BT,
                        const float* __restrict__ bias, u16* __restrict__ C,
                        int M, int N, int K, int row0,
                        const u16* __restrict__ R0,
                        const float* __restrict__ g, const float* __restrict__ be,
                        const float* __restrict__ rmv, const float* __restrict__ rvv,
                        const float* __restrict__ alpha,
                        const float* __restrict__ saw, const float* __restrict__ sab) {
    __shared__ __align__(16) u16 SL[24576];  // 48 KB
    const int tid  = threadIdx.x;
    const int wave = tid >> 6, lane = tid & 63;
    const int wm = wave >> 1, wn = wave & 1;      // 4M x 2N wave grid
    const int quad = lane >> 4, l16 = lane & 15;

    // XCD-aware bijective block swizzle (m204)
    const unsigned gx = gridDim.x;
    unsigned lin = blockIdx.y * gx + blockIdx.x;
    const unsigned nwg = gx * gridDim.y;
    const unsigned q8 = nwg >> 3, r8 = nwg & 7;
    const unsigned xcd = lin & 7, loc = lin >> 3;
    lin = (xcd < r8 ? xcd * (q8 + 1) : r8 * (q8 + 1) + (xcd - r8) * q8) + loc;
    const int m0 = (int)(lin / gx) * 256, n0 = (int)(lin % gx) * 128;

    const int srow = lane >> 2;                                   // 0..15
    const int scol = (((lane & 3) ^ ((srow >> 1) & 3)) * 8);      // swizzled source chunk
    const size_t aoff0 = (size_t)(m0 + wave * 32 + srow) * K + scol;
    const size_t aoff1 = aoff0 + (size_t)16 * K;
    const size_t boff  = (size_t)(n0 + wave * 16 + srow) * K + scol;

    const int cfrag = (quad ^ ((l16 >> 1) & 3)) * 8;

    f32x4 acc[4][4] = {};
    const int niter = K >> 5;

    auto stage = [&](int buf, size_t kn) {
        glds16(A  + aoff0 + kn, SL + buf * 8192 + wave * 1024);
        glds16(A  + aoff1 + kn, SL + buf * 8192 + wave * 1024 + 512);
        glds16(BT + boff  + kn, SL + 16384 + buf * 4096 + wave * 512);
    };

    auto kstep = [&](int cur, int kt) {
        __syncthreads();
        if (kt + 1 < niter) stage(cur ^ 1, (size_t)(kt + 1) << 5);
        const u16* ab = SL + cur * 8192;
        const u16* bb = SL + 16384 + cur * 4096;
        bf16x8 af[4], bfr[4];
        #pragma unroll
        for (int i = 0; i < 4; i++)
            af[i] = *(const bf16x8*)&ab[(wm * 64 + i * 16 + l16) * 32 + cfrag];
        #pragma unroll
        for (int j = 0; j < 4; j++)
            bfr[j] = *(const bf16x8*)&bb[(wn * 64 + j * 16 + l16) * 32 + cfrag];
        #pragma unroll
        for (int i = 0; i < 4; i++)
            #pragma unroll
            for (int j = 0; j < 4; j++)
                acc[i][j] = __builtin_amdgcn_mfma_f32_16x16x32_bf16(af[i], bfr[j], acc[i][j], 0, 0, 0);
    };

    stage(0, 0);
    int kt = 0;
    for (; kt + 2 <= niter; kt += 2) { kstep(0, kt); kstep(1, kt + 1); }
    if (kt < niter) kstep(kt & 1, kt);

    __syncthreads();

    float alphav = 0.f;
    if (EPI == 1) alphav = alpha[0];

    float biasv[4], k0v[4], k1v[4];
    #pragma unroll
    for (int j = 0; j < 4; j++) {
        const int col = n0 + wn * 64 + j * 16 + l16;
        biasv[j] = bias[col];
        if (EPI == 1) {
            float sc = g[col] * rsqrtf(rvv[col] + 1e-5f);
            k1v[j] = sc + alphav;
            k0v[j] = be[col] - rmv[col] * sc;
        }
    }

    const int dup = l16 & 1;
    const int pr  = l16 >> 1;
    u16* Crow = C + (size_t)(m0 + wm * 64 + quad * 4 + 2 * dup) * N
                  + (n0 + wn * 64 + pr * 2);

    auto emit = [&]() {
        #pragma unroll
        for (int i = 0; i < 4; i++) {
            float swv4[4], sbv4[4];
            if (EPI == 2) {
                #pragma unroll
                for (int r = 0; r < 4; r++) {
                    const int row = row0 + m0 + wm * 64 + i * 16 + quad * 4 + r;
                    const int bidx = row / 196;
                    swv4[r] = saw[bidx]; sbv4[r] = sab[bidx];
                }
            }
            #pragma unroll
            for (int j = 0; j < 4; j++) {
                float vv[4];
                #pragma unroll
                for (int r = 0; r < 4; r++) {
                    float v = acc[i][j][r] + biasv[j];
                    if (EPI == 1) {
                        const int rowL = (wm & 1) * 64 + i * 16 + quad * 4 + r;
                        const int colp = wn * 64 + j * 16 + (l16 & ~1);
                        unsigned rd = *(const unsigned*)&SL[rowL * 128 + colp];
                        unsigned fb = dup ? (rd & 0xffff0000u) : (rd << 16);
                        union { unsigned u; float f; } cc; cc.u = fb;
                        float x = v + cc.f;
                        v = fmaf(x, k1v[j], k0v[j]);
                    } else if (EPI == 2) {
                        float w = fmaf(swv4[r], v, sbv4[r]);
                        v = v / (1.f + __expf(-w * v));
                    }
                    vv[r] = v;
                }
                unsigned D[4];
                #pragma unroll
                for (int r = 0; r < 4; r++) {
                    float o  = __shfl_xor(vv[r], 1, 64);
                    float lo = dup ? o : vv[r];
                    float hi = dup ? vv[r] : o;
                    D[r] = cvtpk(lo, hi);
                }
                unsigned s0 = dup ? D[2] : D[0];
                unsigned s1 = dup ? D[3] : D[1];
                u16* p = Crow + (size_t)i * 16 * N + j * 16;
                *(unsigned*)p       = s0;
                *(unsigned*)(p + N) = s1;
            }
        }
    };

    if (EPI == 1) {
        #pragma unroll
        for (int h = 0; h < 2; h++) {
            for (int c = tid; c < 2048; c += 512) {
                int row = c >> 4, colc = (c & 15) * 8;
                *(u16x8*)&SL[row * 128 + colc] =
                    *(const u16x8*)&R0[(size_t)(m0 + h * 128 + row) * N + n0 + colc];
            }
            __syncthreads();
            if ((wm >> 1) == h) emit();
            __syncthreads();
        }
    } else {
        emit();
    }
}

// ---------------------------------------------------------------------------
// gemm_w2: fill-matched variant for W2 (N=256). 256x64 tile, 4 waves
// (256 thr), wave tile 64x64, BK=32, LDS 40 KB -> 4 blocks/CU.
// Rationale: W2 at 256x128 tiles = 392 blocks vs ~768 residency slots (51%
// machine fill). 256x64 tiles -> 784 blocks (full fill) with the SAME
// per-wave work-per-drain (16 MFMA + 5 glds per K-step) and the same proven
// chunk swizzle / sync skeleton / pair-pack epilogue. EPI=1 only.
// ---------------------------------------------------------------------------
template<int EPI>
__launch_bounds__(256, 4)
__global__ void gemm_w2(const u16* __restrict__ A, const u16* __restrict__ BT,
                        const float* __restrict__ bias, u16* __restrict__ C,
                        int M, int N, int K, int row0,
                        const u16* __restrict__ R0,
                        const float* __restrict__ g, const float* __restrict__ be,
                        const float* __restrict__ rmv, const float* __restrict__ rvv,
                        const float* __restrict__ alpha,
                        const float* __restrict__ saw, const float* __restrict__ sab) {
    // A: 2 bufs x 8192 elems ([256 rows][32 k]) at 0; B: 2 bufs x 2048 at 16384
    __shared__ __align__(16) u16 SL[20480];  // 40 KB
    const int tid  = threadIdx.x;
    const int wave = tid >> 6, lane = tid & 63;
    const int quad = lane >> 4, l16 = lane & 15;

    // XCD-aware bijective block swizzle (m204)
    const unsigned gx = gridDim.x;
    unsigned lin = blockIdx.y * gx + blockIdx.x;
    const unsigned nwg = gx * gridDim.y;
    const unsigned q8 = nwg >> 3, r8 = nwg & 7;
    const unsigned xcd = lin & 7, loc = lin >> 3;
    lin = (xcd < r8 ? xcd * (q8 + 1) : r8 * (q8 + 1) + (xcd - r8) * q8) + loc;
    const int m0 = (int)(lin / gx) * 256, n0 = (int)(lin % gx) * 64;

    const int srow = lane >> 2;                                   // 0..15
    const int scol = (((lane & 3) ^ ((srow >> 1) & 3)) * 8);      // swizzled source chunk
    // A: wave stages rows [wave*64, +64) via 4 glds (16 rows each).
    size_t aoff[4];
    #pragma unroll
    for (int t = 0; t < 4; t++)
        aoff[t] = (size_t)(m0 + wave * 64 + t * 16 + srow) * K + scol;
    // B: wave stages rows [n0 + wave*16, +16) via 1 glds.
    const size_t boff = (size_t)(n0 + wave * 16 + srow) * K + scol;

    const int cfrag = (quad ^ ((l16 >> 1) & 3)) * 8;

    f32x4 acc[4][4] = {};
    const int niter = K >> 5;

    auto stage = [&](int buf, size_t kn) {
        #pragma unroll
        for (int t = 0; t < 4; t++)
            glds16(A + aoff[t] + kn, SL + buf * 8192 + (wave * 64 + t * 16) * 32);
        glds16(BT + boff + kn, SL + 16384 + buf * 2048 + wave * 512);
    };

    auto kstep = [&](int cur, int kt) {
        __syncthreads();
        if (kt + 1 < niter) stage(cur ^ 1, (size_t)(kt + 1) << 5);
        const u16* ab = SL + cur * 8192;
        const u16* bb = SL + 16384 + cur * 2048;
        bf16x8 af[4], bfr[4];
        #pragma unroll
        for (int i = 0; i < 4; i++)
            af[i] = *(const bf16x8*)&ab[(wave * 64 + i * 16 + l16) * 32 + cfrag];
        #pragma unroll
        for (int j = 0; j < 4; j++)
            bfr[j] = *(const bf16x8*)&bb[(j * 16 + l16) * 32 + cfrag];
        #pragma unroll
        for (int i = 0; i < 4; i++)
            #pragma unroll
            for (int j = 0; j < 4; j++)
                acc[i][j] = __builtin_amdgcn_mfma_f32_16x16x32_bf16(af[i], bfr[j], acc[i][j], 0, 0, 0);
    };

    stage(0, 0);
    int kt = 0;
    for (; kt + 2 <= niter; kt += 2) { kstep(0, kt); kstep(1, kt + 1); }
    if (kt < niter) kstep(kt & 1, kt);

    __syncthreads();

    const float alphav = (EPI == 1) ? alpha[0] : 0.f;
    const int dup = l16 & 1, pr = l16 >> 1;

    if (EPI == 1) {
        // restage residual tile [256][64] into SL (32 KB, one pass)
        for (int c = tid; c < 2048; c += 256) {
            int row = c >> 3, colc = (c & 7) * 8;
            *(u16x8*)&SL[row * 64 + colc] =
                *(const u16x8*)&R0[(size_t)(m0 + row) * N + n0 + colc];
        }
        __syncthreads();
    }

    float biasv[4], k0p[4][2], k1p[4][2];
    #pragma unroll
    for (int j = 0; j < 4; j++) {
        biasv[j] = bias[n0 + j * 16 + l16];
        if (EPI == 1) {
            #pragma unroll
            for (int p = 0; p < 2; p++) {
                const int col = n0 + j * 16 + pr * 2 + p;
                const float sc = g[col] * rsqrtf(rvv[col] + 1e-5f);
                k1p[j][p] = sc + alphav;
                k0p[j][p] = be[col] - rmv[col] * sc;
            }
        }
    }

    u16* Crow = C + (size_t)(m0 + wave * 64 + quad * 4 + 2 * dup) * N + (n0 + pr * 2);
    const int r0i = 2 * dup, r1i = r0i + 1;

    #pragma unroll
    for (int i = 0; i < 4; i++) {
        #pragma unroll
        for (int j = 0; j < 4; j++) {
            float vv[4];
            #pragma unroll
            for (int r = 0; r < 4; r++) vv[r] = acc[i][j][r] + biasv[j];
            float ot[4];
            #pragma unroll
            for (int r = 0; r < 4; r++) ot[r] = __shfl_xor(vv[r], 1, 64);
            float lo0 = dup ? ot[r0i] : vv[r0i], hi0 = dup ? vv[r0i] : ot[r0i];
            float lo1 = dup ? ot[r1i] : vv[r1i], hi1 = dup ? vv[r1i] : ot[r1i];
            if (EPI == 1) {
                const int rowL = wave * 64 + i * 16 + quad * 4 + r0i;
                const int colp = j * 16 + pr * 2;
                const unsigned rd0 = *(const unsigned*)&SL[rowL * 64 + colp];
                const unsigned rd1 = *(const unsigned*)&SL[(rowL + 1) * 64 + colp];
                lo0 = fmaf(lo0 + b2f((u16)(rd0 & 0xffff)), k1p[j][0], k0p[j][0]);
                hi0 = fmaf(hi0 + b2f((u16)(rd0 >> 16)),    k1p[j][1], k0p[j][1]);
                lo1 = fmaf(lo1 + b2f((u16)(rd1 & 0xffff)), k1p[j][0], k0p[j][0]);
                hi1 = fmaf(hi1 + b2f((u16)(rd1 >> 16)),    k1p[j][1], k0p[j][1]);
            }
            u16* p = Crow + (size_t)i * 16 * N + j * 16;
            *(unsigned*)p       = cvtpk(lo0, hi0);
            *(unsigned*)(p + N) = cvtpk(lo1, hi1);
        }
    }
}

// ---------------------------------------------------------------------------
// MFMA flash attention: one block per (local b, h), 4 waves.
// V staging vectorized (u16x8 row reads + scalar transposed LDS writes).
// ---------------------------------------------------------------------------
__launch_bounds__(256)
__global__ void attn_kernel(const u16* __restrict__ qkv, u16* __restrict__ o) {
    __shared__ __align__(16) u16 Kb[224 * 32];
    __shared__ __align__(16) u16 Vt[32 * 232];
    __shared__ __align__(16) u16 Pl[4][16 * 232];
    const int tid  = threadIdx.x;
    const int wave = tid >> 6, lane = tid & 63;
    const int quad = lane >> 4, l16 = lane & 15;
    const int b = blockIdx.x >> 3, h = blockIdx.x & 7;
    const u16* qg = qkv + (size_t)b * 196 * 768 + h * 32;
    const float scale = 0.17677669529663687f; // 1/sqrt(32)

    for (int idx = tid; idx < 896; idx += 256) {
        int row = idx >> 2, dp = (idx & 3) * 8;
        u16x8 kv = {};
        if (row < 196) kv = *(const u16x8*)&qg[(size_t)row * 768 + 256 + dp];
        *(u16x8*)&Kb[row * 32 + dp] = kv;
    }
    for (int idx = tid; idx < 896; idx += 256) {
        int row = idx >> 2, dp = (idx & 3) * 8;
        u16x8 vv = {};
        if (row < 196) vv = *(const u16x8*)&qg[(size_t)row * 768 + 512 + dp];
        #pragma unroll
        for (int e = 0; e < 8; e++) Vt[(dp + e) * 232 + row] = vv[e];
    }
    for (int c = lane; c < 16 * 24; c += 64) {
        int m = c / 24, cc = 208 + (c % 24);
        Pl[wave][m * 232 + cc] = 0;
    }
    __syncthreads();

    for (int t = wave; t < 13; t += 4) {
        const int m0 = t * 16;
        bf16x8 aq = {};
        const int qrow = m0 + l16;
        if (qrow < 196) aq = *(const bf16x8*)&qg[(size_t)qrow * 768 + quad * 8];

        f32x4 s[13];
        #pragma unroll
        for (int ct = 0; ct < 13; ct++) {
            bf16x8 bk = *(const bf16x8*)&Kb[(ct * 16 + l16) * 32 + quad * 8];
            s[ct] = __builtin_amdgcn_mfma_f32_16x16x32_bf16(aq, bk, (f32x4){0.f, 0.f, 0.f, 0.f}, 0, 0, 0);
        }
        if (l16 >= 4) {
            #pragma unroll
            for (int r = 0; r < 4; r++) s[12][r] = -1e30f;
        }
        float mx[4] = {-1e30f, -1e30f, -1e30f, -1e30f};
        #pragma unroll
        for (int ct = 0; ct < 13; ct++)
            #pragma unroll
            for (int r = 0; r < 4; r++) mx[r] = fmaxf(mx[r], s[ct][r]);
        #pragma unroll
        for (int off = 1; off < 16; off <<= 1)
            #pragma unroll
            for (int r = 0; r < 4; r++) mx[r] = fmaxf(mx[r], __shfl_xor(mx[r], off, 64));
        float sum[4] = {0.f, 0.f, 0.f, 0.f};
        #pragma unroll
        for (int ct = 0; ct < 13; ct++) {
            #pragma unroll
            for (int r = 0; r < 4; r++) {
                float p = __expf((s[ct][r] - mx[r]) * scale);
                sum[r] += p;
                Pl[wave][(quad * 4 + r) * 232 + ct * 16 + l16] = f2b(p);
            }
        }
        #pragma unroll
        for (int off = 1; off < 16; off <<= 1)
            #pragma unroll
            for (int r = 0; r < 4; r++) sum[r] += __shfl_xor(sum[r], off, 64);
        float inv[4];
        #pragma unroll
        for (int r = 0; r < 4; r++) inv[r] = 1.f / sum[r];

        #pragma unroll
        for (int nt = 0; nt < 2; nt++) {
            f32x4 ao = {0.f, 0.f, 0.f, 0.f};
            #pragma unroll
            for (int kc = 0; kc < 7; kc++) {
                bf16x8 ap = *(const bf16x8*)&Pl[wave][l16 * 232 + kc * 32 + quad * 8];
                bf16x8 bv = *(const bf16x8*)&Vt[(nt * 16 + l16) * 232 + kc * 32 + quad * 8];
                ao = __builtin_amdgcn_mfma_f32_16x16x32_bf16(ap, bv, ao, 0, 0, 0);
            }
            #pragma unroll
            for (int r = 0; r < 4; r++) {
                const int gm = m0 + quad * 4 + r;
                if (gm < 196)
                    o[((size_t)b * 196 + gm) * 256 + h * 32 + nt * 16 + l16] = f2b(ao[r] * inv[r]);
            }
        }
    }
}

// ---------------------------------------------------------------------------
extern "C" void kernel_launch(void* const* d_in, const int* in_sizes, int n_in,
                              void* d_out, int out_size, void* d_ws, size_t ws_size,
                              hipStream_t stream) {
    const float* x      = (const float*)d_in[0];
    const float* Wqkv   = (const float*)d_in[1];
    const float* bqkv   = (const float*)d_in[2];
    const float* Wproj  = (const float*)d_in[3];
    const float* bproj  = (const float*)d_in[4];
    const float* W1     = (const float*)d_in[5];
    const float* b1     = (const float*)d_in[6];
    const float* W2     = (const float*)d_in[7];
    const float* b2     = (const float*)d_in[8];
    const float* saw    = (const float*)d_in[9];
    const float* sab    = (const float*)d_in[10];
    const float* alpha1 = (const float*)d_in[11];
    const float* g1     = (const float*)d_in[12];
    const float* be1    = (const float*)d_in[13];
    const float* rm1    = (const float*)d_in[14];
    const float* rv1    = (const float*)d_in[15];
    const float* alpha2 = (const float*)d_in[16];
    const float* g2     = (const float*)d_in[17];
    const float* be2    = (const float*)d_in[18];
    const float* rm2    = (const float*)d_in[19];
    const float* rv2    = (const float*)d_in[20];

    const int B = 256, Cc = 256, Np = 196, CM = 2048;
    const int M = B * Np; // 50176

    auto al = [](size_t s) { return (s + 255) & ~(size_t)255; };
    char* ws = (char*)d_ws;
    const size_t o_t0  = 0;
    const size_t o_t1  = o_t0 + al((size_t)M * Cc * 2);
    const size_t o_wq  = o_t1 + al((size_t)M * Cc * 2);
    const size_t o_wp  = o_wq + al((size_t)768 * Cc * 2);
    const size_t o_w1  = o_wp + al((size_t)Cc * Cc * 2);
    const size_t o_w2  = o_w1 + al((size_t)Cc * CM * 2);
    const size_t o_scr = o_w2 + al((size_t)CM * Cc * 2);
    const size_t S = (ws_size > o_scr) ? ws_size - o_scr : 0;

    u16* t0     = (u16*)(ws + o_t0);
    u16* t1b    = (u16*)(ws + o_t1);
    u16* WqkvT  = (u16*)(ws + o_wq);
    u16* WprojT = (u16*)(ws + o_wp);
    u16* W1T    = (u16*)(ws + o_w1);
    u16* W2T    = (u16*)(ws + o_w2);
    u16* scr    = (u16*)(ws + o_scr);
    u16* t2     = t0;            // alias: t0 dead after proj epilogue
    u16* obuf   = (u16*)d_out;   // bf16 scratch in f32 d_out; fully rewritten by final btrans
    float* out  = (float*)d_out;

    // chunk counts: M-chunks must stay multiples of 256.
    int nq = 1; while (nq < 4 && ((size_t)(M / nq) * 768 * 2) > S) nq *= 2;
    const int nf_opts[6] = {1, 2, 4, 14, 28, 56};
    int nf = 56;
    for (int i = 0; i < 6; ++i) {
        if (((size_t)(M / nf_opts[i]) * CM * 2) <= S) { nf = nf_opts[i]; break; }
    }
    const int Mq = M / nq, Bq = B / nq;
    const int Mf = M / nf;

    dim3 tb(32, 8, 1);
    // x f32 [B][C][N] -> t0 bf16 [B][N][C]
    btrans_f2b<<<dim3((Np + 31) / 32, (Cc + 31) / 32, B), tb, 0, stream>>>(x, t0, Cc, Np);
    // weights f32 [K][N] -> bf16 [N][K]
    btrans_f2b<<<dim3(768 / 32, Cc / 32, 1), tb, 0, stream>>>(Wqkv,  WqkvT,  Cc, 768);
    btrans_f2b<<<dim3(Cc  / 32, Cc / 32, 1), tb, 0, stream>>>(Wproj, WprojT, Cc, Cc);
    btrans_f2b<<<dim3(CM  / 32, Cc / 32, 1), tb, 0, stream>>>(W1,    W1T,    Cc, CM);
    btrans_f2b<<<dim3(Cc  / 32, CM / 32, 1), tb, 0, stream>>>(W2,    W2T,    CM, Cc);

    // qkv + attention, chunked over batches
    for (int c = 0; c < nq; ++c) {
        gemm_bt<0><<<dim3(768 / 128, Mq / 256), 512, 0, stream>>>(
            t0 + (size_t)c * Mq * Cc, WqkvT, bqkv, scr, Mq, 768, Cc, 0,
            nullptr, nullptr, nullptr, nullptr, nullptr, nullptr, nullptr, nullptr);
        attn_kernel<<<dim3(Bq * 8), 256, 0, stream>>>(scr, obuf + (size_t)c * Mq * Cc);
    }

    // t1 = RepBN1(t0 + obuf @ Wproj + bproj)
    gemm_bt<1><<<dim3(Cc / 128, M / 256), 512, 0, stream>>>(
        obuf, WprojT, bproj, t1b, M, Cc, Cc, 0,
        t0, g1, be1, rm1, rv1, alpha1, nullptr, nullptr);

    // FFN, chunked over rows: W1 on gemm_bt, W2 on the fill-matched gemm_w2
    for (int c = 0; c < nf; ++c) {
        gemm_bt<2><<<dim3(CM / 128, Mf / 256), 512, 0, stream>>>(
            t1b + (size_t)c * Mf * Cc, W1T, b1, scr, Mf, CM, Cc, c * Mf,
            nullptr, nullptr, nullptr, nullptr, nullptr, nullptr, saw, sab);
        gemm_w2<1><<<dim3(Cc / 64, Mf / 256), 256, 0, stream>>>(
            scr, W2T, b2, t2 + (size_t)c * Mf * Cc, Mf, Cc, CM, 0,
            t1b + (size_t)c * Mf * Cc, g2, be2, rm2, rv2, alpha2, nullptr, nullptr);
    }

    // t2 bf16 [B][N][C] -> out f32 [B][C][N]
    btrans_b2f<<<dim3((Cc + 31) / 32, (Np + 31) / 32, B), tb, 0, stream>>>(t2, out, Np, Cc);
}

// Round 15
// 518.689 us; speedup vs baseline: 1.4068x; 1.0861x over previous
//
#include <hip/hip_runtime.h>

using u16 = unsigned short;

typedef __bf16 bf16x8 __attribute__((ext_vector_type(8)));
typedef u16    u16x8  __attribute__((ext_vector_type(8)));
typedef float  f32x4  __attribute__((ext_vector_type(4)));

__device__ __forceinline__ float b2f(u16 u) {
    union { unsigned int i; float f; } c; c.i = ((unsigned int)u) << 16; return c.f;
}
__device__ __forceinline__ u16 f2b(float f) {
    union { float f; unsigned int i; } c; c.f = f;
    unsigned int i = c.i;
    return (u16)((i + 0x7FFFu + ((i >> 16) & 1u)) >> 16);
}
__device__ __forceinline__ unsigned cvtpk(float lo, float hi) {
    unsigned d;
    asm("v_cvt_pk_bf16_f32 %0, %1, %2" : "=v"(d) : "v"(lo), "v"(hi));
    return d;
}

#define AS1 __attribute__((address_space(1)))
#define AS3 __attribute__((address_space(3)))
__device__ __forceinline__ void glds16(const u16* g, u16* l) {
    __builtin_amdgcn_global_load_lds((const AS1 void*)(const void*)g,
                                     (AS3 void*)(void*)l, 16, 0, 0);
}

// ---------------------------------------------------------------------------
// Batched transpose + convert f32 -> bf16: in[b][R][C] f32 -> out[b][C][R] bf16
// ---------------------------------------------------------------------------
__global__ void btrans_f2b(const float* __restrict__ in, u16* __restrict__ out, int R, int C) {
    __shared__ u16 tile[32][33];
    const int c0 = blockIdx.x * 32, r0 = blockIdx.y * 32;
    const size_t base = (size_t)blockIdx.z * R * C;
    const int tx = threadIdx.x, ty = threadIdx.y;
    #pragma unroll
    for (int i = ty; i < 32; i += 8) {
        int r = r0 + i, c = c0 + tx;
        tile[i][tx] = (r < R && c < C) ? f2b(in[base + (size_t)r * C + c]) : (u16)0;
    }
    __syncthreads();
    #pragma unroll
    for (int i = ty; i < 32; i += 8) {
        int c = c0 + i, r = r0 + tx;
        if (c < C && r < R) out[base + (size_t)c * R + r] = tile[tx][i];
    }
}

// Batched transpose + convert bf16 -> f32: in[b][R][C] bf16 -> out[b][C][R] f32
__global__ void btrans_b2f(const u16* __restrict__ in, float* __restrict__ out, int R, int C) {
    __shared__ u16 tile[32][33];
    const int c0 = blockIdx.x * 32, r0 = blockIdx.y * 32;
    const size_t base = (size_t)blockIdx.z * R * C;
    const int tx = threadIdx.x, ty = threadIdx.y;
    #pragma unroll
    for (int i = ty; i < 32; i += 8) {
        int r = r0 + i, c = c0 + tx;
        tile[i][tx] = (r < R && c < C) ? in[base + (size_t)r * C + c] : (u16)0;
    }
    __syncthreads();
    #pragma unroll
    for (int i = ty; i < 32; i += 8) {
        int c = c0 + i, r = r0 + tx;
        if (c < C && r < R) out[base + (size_t)c * R + r] = b2f(tile[tx][i]);
    }
}

// ---------------------------------------------------------------------------
// GEMM: C[M,N] = epilogue(A[M,K] @ BT[N,K]^T + bias)   (A,BT,C bf16)
// Proven 515-us state: 256x128 block tile, BK=32, 8 waves (4M x 2N), 64x64
// per-wave tiles. 2-buffer, one-__syncthreads-per-K-step skeleton.
// LDS 48 KB (A 2x16K, B 2x8K) -> 3 blocks/CU. Pair-pack epilogue.
// Local optimum confirmed: 7 structural variants (wave count, tile shape,
// BK=64, register-resident panels x3, 8-phase counted-vmcnt, fill-matched
// 256x64) all regressed or were neutral against this configuration.
// EPI: 0 = bias only; 1 = bias+residual+RepBN; 2 = bias+SpatialSiLU
// ---------------------------------------------------------------------------
template<int EPI>
__launch_bounds__(512, 4)
__global__ void gemm_bt(const u16* __restrict__ A, const u16* __restrict__ BT,
                        const float* __restrict__ bias, u16* __restrict__ C,
                        int M, int N, int K, int row0,
                        const u16* __restrict__ R0,
                        const float* __restrict__ g, const float* __restrict__ be,
                        const float* __restrict__ rmv, const float* __restrict__ rvv,
                        const float* __restrict__ alpha,
                        const float* __restrict__ saw, const float* __restrict__ sab) {
    __shared__ __align__(16) u16 SL[24576];  // 48 KB
    const int tid  = threadIdx.x;
    const int wave = tid >> 6, lane = tid & 63;
    const int wm = wave >> 1, wn = wave & 1;      // 4M x 2N wave grid
    const int quad = lane >> 4, l16 = lane & 15;

    // XCD-aware bijective block swizzle (m204)
    const unsigned gx = gridDim.x;
    unsigned lin = blockIdx.y * gx + blockIdx.x;
    const unsigned nwg = gx * gridDim.y;
    const unsigned q8 = nwg >> 3, r8 = nwg & 7;
    const unsigned xcd = lin & 7, loc = lin >> 3;
    lin = (xcd < r8 ? xcd * (q8 + 1) : r8 * (q8 + 1) + (xcd - r8) * q8) + loc;
    const int m0 = (int)(lin / gx) * 256, n0 = (int)(lin % gx) * 128;

    const int srow = lane >> 2;                                   // 0..15
    const int scol = (((lane & 3) ^ ((srow >> 1) & 3)) * 8);      // swizzled source chunk
    const size_t aoff0 = (size_t)(m0 + wave * 32 + srow) * K + scol;
    const size_t aoff1 = aoff0 + (size_t)16 * K;
    const size_t boff  = (size_t)(n0 + wave * 16 + srow) * K + scol;

    const int cfrag = (quad ^ ((l16 >> 1) & 3)) * 8;

    f32x4 acc[4][4] = {};
    const int niter = K >> 5;

    auto stage = [&](int buf, size_t kn) {
        glds16(A  + aoff0 + kn, SL + buf * 8192 + wave * 1024);
        glds16(A  + aoff1 + kn, SL + buf * 8192 + wave * 1024 + 512);
        glds16(BT + boff  + kn, SL + 16384 + buf * 4096 + wave * 512);
    };

    auto kstep = [&](int cur, int kt) {
        __syncthreads();
        if (kt + 1 < niter) stage(cur ^ 1, (size_t)(kt + 1) << 5);
        const u16* ab = SL + cur * 8192;
        const u16* bb = SL + 16384 + cur * 4096;
        bf16x8 af[4], bfr[4];
        #pragma unroll
        for (int i = 0; i < 4; i++)
            af[i] = *(const bf16x8*)&ab[(wm * 64 + i * 16 + l16) * 32 + cfrag];
        #pragma unroll
        for (int j = 0; j < 4; j++)
            bfr[j] = *(const bf16x8*)&bb[(wn * 64 + j * 16 + l16) * 32 + cfrag];
        #pragma unroll
        for (int i = 0; i < 4; i++)
            #pragma unroll
            for (int j = 0; j < 4; j++)
                acc[i][j] = __builtin_amdgcn_mfma_f32_16x16x32_bf16(af[i], bfr[j], acc[i][j], 0, 0, 0);
    };

    stage(0, 0);
    int kt = 0;
    for (; kt + 2 <= niter; kt += 2) { kstep(0, kt); kstep(1, kt + 1); }
    if (kt < niter) kstep(kt & 1, kt);

    __syncthreads();

    float alphav = 0.f;
    if (EPI == 1) alphav = alpha[0];

    float biasv[4], k0v[4], k1v[4];
    #pragma unroll
    for (int j = 0; j < 4; j++) {
        const int col = n0 + wn * 64 + j * 16 + l16;
        biasv[j] = bias[col];
        if (EPI == 1) {
            float sc = g[col] * rsqrtf(rvv[col] + 1e-5f);
            k1v[j] = sc + alphav;
            k0v[j] = be[col] - rmv[col] * sc;
        }
    }

    const int dup = l16 & 1;
    const int pr  = l16 >> 1;
    u16* Crow = C + (size_t)(m0 + wm * 64 + quad * 4 + 2 * dup) * N
                  + (n0 + wn * 64 + pr * 2);

    auto emit = [&]() {
        #pragma unroll
        for (int i = 0; i < 4; i++) {
            float swv4[4], sbv4[4];
            if (EPI == 2) {
                #pragma unroll
                for (int r = 0; r < 4; r++) {
                    const int row = row0 + m0 + wm * 64 + i * 16 + quad * 4 + r;
                    const int bidx = row / 196;
                    swv4[r] = saw[bidx]; sbv4[r] = sab[bidx];
                }
            }
            #pragma unroll
            for (int j = 0; j < 4; j++) {
                float vv[4];
                #pragma unroll
                for (int r = 0; r < 4; r++) {
                    float v = acc[i][j][r] + biasv[j];
                    if (EPI == 1) {
                        const int rowL = (wm & 1) * 64 + i * 16 + quad * 4 + r;
                        const int colp = wn * 64 + j * 16 + (l16 & ~1);
                        unsigned rd = *(const unsigned*)&SL[rowL * 128 + colp];
                        unsigned fb = dup ? (rd & 0xffff0000u) : (rd << 16);
                        union { unsigned u; float f; } cc; cc.u = fb;
                        float x = v + cc.f;
                        v = fmaf(x, k1v[j], k0v[j]);
                    } else if (EPI == 2) {
                        float w = fmaf(swv4[r], v, sbv4[r]);
                        v = v / (1.f + __expf(-w * v));
                    }
                    vv[r] = v;
                }
                unsigned D[4];
                #pragma unroll
                for (int r = 0; r < 4; r++) {
                    float o  = __shfl_xor(vv[r], 1, 64);
                    float lo = dup ? o : vv[r];
                    float hi = dup ? vv[r] : o;
                    D[r] = cvtpk(lo, hi);
                }
                unsigned s0 = dup ? D[2] : D[0];
                unsigned s1 = dup ? D[3] : D[1];
                u16* p = Crow + (size_t)i * 16 * N + j * 16;
                *(unsigned*)p       = s0;
                *(unsigned*)(p + N) = s1;
            }
        }
    };

    if (EPI == 1) {
        #pragma unroll
        for (int h = 0; h < 2; h++) {
            for (int c = tid; c < 2048; c += 512) {
                int row = c >> 4, colc = (c & 15) * 8;
                *(u16x8*)&SL[row * 128 + colc] =
                    *(const u16x8*)&R0[(size_t)(m0 + h * 128 + row) * N + n0 + colc];
            }
            __syncthreads();
            if ((wm >> 1) == h) emit();
            __syncthreads();
        }
    } else {
        emit();
    }
}

// ---------------------------------------------------------------------------
// MFMA flash attention: one block per (local b, h), 4 waves.
// V staging vectorized (u16x8 row reads + scalar transposed LDS writes).
// ---------------------------------------------------------------------------
__launch_bounds__(256)
__global__ void attn_kernel(const u16* __restrict__ qkv, u16* __restrict__ o) {
    __shared__ __align__(16) u16 Kb[224 * 32];
    __shared__ __align__(16) u16 Vt[32 * 232];
    __shared__ __align__(16) u16 Pl[4][16 * 232];
    const int tid  = threadIdx.x;
    const int wave = tid >> 6, lane = tid & 63;
    const int quad = lane >> 4, l16 = lane & 15;
    const int b = blockIdx.x >> 3, h = blockIdx.x & 7;
    const u16* qg = qkv + (size_t)b * 196 * 768 + h * 32;
    const float scale = 0.17677669529663687f; // 1/sqrt(32)

    for (int idx = tid; idx < 896; idx += 256) {
        int row = idx >> 2, dp = (idx & 3) * 8;
        u16x8 kv = {};
        if (row < 196) kv = *(const u16x8*)&qg[(size_t)row * 768 + 256 + dp];
        *(u16x8*)&Kb[row * 32 + dp] = kv;
    }
    for (int idx = tid; idx < 896; idx += 256) {
        int row = idx >> 2, dp = (idx & 3) * 8;
        u16x8 vv = {};
        if (row < 196) vv = *(const u16x8*)&qg[(size_t)row * 768 + 512 + dp];
        #pragma unroll
        for (int e = 0; e < 8; e++) Vt[(dp + e) * 232 + row] = vv[e];
    }
    for (int c = lane; c < 16 * 24; c += 64) {
        int m = c / 24, cc = 208 + (c % 24);
        Pl[wave][m * 232 + cc] = 0;
    }
    __syncthreads();

    for (int t = wave; t < 13; t += 4) {
        const int m0 = t * 16;
        bf16x8 aq = {};
        const int qrow = m0 + l16;
        if (qrow < 196) aq = *(const bf16x8*)&qg[(size_t)qrow * 768 + quad * 8];

        f32x4 s[13];
        #pragma unroll
        for (int ct = 0; ct < 13; ct++) {
            bf16x8 bk = *(const bf16x8*)&Kb[(ct * 16 + l16) * 32 + quad * 8];
            s[ct] = __builtin_amdgcn_mfma_f32_16x16x32_bf16(aq, bk, (f32x4){0.f, 0.f, 0.f, 0.f}, 0, 0, 0);
        }
        if (l16 >= 4) {
            #pragma unroll
            for (int r = 0; r < 4; r++) s[12][r] = -1e30f;
        }
        float mx[4] = {-1e30f, -1e30f, -1e30f, -1e30f};
        #pragma unroll
        for (int ct = 0; ct < 13; ct++)
            #pragma unroll
            for (int r = 0; r < 4; r++) mx[r] = fmaxf(mx[r], s[ct][r]);
        #pragma unroll
        for (int off = 1; off < 16; off <<= 1)
            #pragma unroll
            for (int r = 0; r < 4; r++) mx[r] = fmaxf(mx[r], __shfl_xor(mx[r], off, 64));
        float sum[4] = {0.f, 0.f, 0.f, 0.f};
        #pragma unroll
        for (int ct = 0; ct < 13; ct++) {
            #pragma unroll
            for (int r = 0; r < 4; r++) {
                float p = __expf((s[ct][r] - mx[r]) * scale);
                sum[r] += p;
                Pl[wave][(quad * 4 + r) * 232 + ct * 16 + l16] = f2b(p);
            }
        }
        #pragma unroll
        for (int off = 1; off < 16; off <<= 1)
            #pragma unroll
            for (int r = 0; r < 4; r++) sum[r] += __shfl_xor(sum[r], off, 64);
        float inv[4];
        #pragma unroll
        for (int r = 0; r < 4; r++) inv[r] = 1.f / sum[r];

        #pragma unroll
        for (int nt = 0; nt < 2; nt++) {
            f32x4 ao = {0.f, 0.f, 0.f, 0.f};
            #pragma unroll
            for (int kc = 0; kc < 7; kc++) {
                bf16x8 ap = *(const bf16x8*)&Pl[wave][l16 * 232 + kc * 32 + quad * 8];
                bf16x8 bv = *(const bf16x8*)&Vt[(nt * 16 + l16) * 232 + kc * 32 + quad * 8];
                ao = __builtin_amdgcn_mfma_f32_16x16x32_bf16(ap, bv, ao, 0, 0, 0);
            }
            #pragma unroll
            for (int r = 0; r < 4; r++) {
                const int gm = m0 + quad * 4 + r;
                if (gm < 196)
                    o[((size_t)b * 196 + gm) * 256 + h * 32 + nt * 16 + l16] = f2b(ao[r] * inv[r]);
            }
        }
    }
}

// ---------------------------------------------------------------------------
extern "C" void kernel_launch(void* const* d_in, const int* in_sizes, int n_in,
                              void* d_out, int out_size, void* d_ws, size_t ws_size,
                              hipStream_t stream) {
    const float* x      = (const float*)d_in[0];
    const float* Wqkv   = (const float*)d_in[1];
    const float* bqkv   = (const float*)d_in[2];
    const float* Wproj  = (const float*)d_in[3];
    const float* bproj  = (const float*)d_in[4];
    const float* W1     = (const float*)d_in[5];
    const float* b1     = (const float*)d_in[6];
    const float* W2     = (const float*)d_in[7];
    const float* b2     = (const float*)d_in[8];
    const float* saw    = (const float*)d_in[9];
    const float* sab    = (const float*)d_in[10];
    const float* alpha1 = (const float*)d_in[11];
    const float* g1     = (const float*)d_in[12];
    const float* be1    = (const float*)d_in[13];
    const float* rm1    = (const float*)d_in[14];
    const float* rv1    = (const float*)d_in[15];
    const float* alpha2 = (const float*)d_in[16];
    const float* g2     = (const float*)d_in[17];
    const float* be2    = (const float*)d_in[18];
    const float* rm2    = (const float*)d_in[19];
    const float* rv2    = (const float*)d_in[20];

    const int B = 256, Cc = 256, Np = 196, CM = 2048;
    const int M = B * Np; // 50176

    auto al = [](size_t s) { return (s + 255) & ~(size_t)255; };
    char* ws = (char*)d_ws;
    const size_t o_t0  = 0;
    const size_t o_t1  = o_t0 + al((size_t)M * Cc * 2);
    const size_t o_wq  = o_t1 + al((size_t)M * Cc * 2);
    const size_t o_wp  = o_wq + al((size_t)768 * Cc * 2);
    const size_t o_w1  = o_wp + al((size_t)Cc * Cc * 2);
    const size_t o_w2  = o_w1 + al((size_t)Cc * CM * 2);
    const size_t o_scr = o_w2 + al((size_t)CM * Cc * 2);
    const size_t S = (ws_size > o_scr) ? ws_size - o_scr : 0;

    u16* t0     = (u16*)(ws + o_t0);
    u16* t1b    = (u16*)(ws + o_t1);
    u16* WqkvT  = (u16*)(ws + o_wq);
    u16* WprojT = (u16*)(ws + o_wp);
    u16* W1T    = (u16*)(ws + o_w1);
    u16* W2T    = (u16*)(ws + o_w2);
    u16* scr    = (u16*)(ws + o_scr);
    u16* t2     = t0;            // alias: t0 dead after proj epilogue
    u16* obuf   = (u16*)d_out;   // bf16 scratch in f32 d_out; fully rewritten by final btrans
    float* out  = (float*)d_out;

    // chunk counts: M-chunks must stay multiples of 256.
    int nq = 1; while (nq < 4 && ((size_t)(M / nq) * 768 * 2) > S) nq *= 2;
    const int nf_opts[6] = {1, 2, 4, 14, 28, 56};
    int nf = 56;
    for (int i = 0; i < 6; ++i) {
        if (((size_t)(M / nf_opts[i]) * CM * 2) <= S) { nf = nf_opts[i]; break; }
    }
    const int Mq = M / nq, Bq = B / nq;
    const int Mf = M / nf;

    dim3 tb(32, 8, 1);
    // x f32 [B][C][N] -> t0 bf16 [B][N][C]
    btrans_f2b<<<dim3((Np + 31) / 32, (Cc + 31) / 32, B), tb, 0, stream>>>(x, t0, Cc, Np);
    // weights f32 [K][N] -> bf16 [N][K]
    btrans_f2b<<<dim3(768 / 32, Cc / 32, 1), tb, 0, stream>>>(Wqkv,  WqkvT,  Cc, 768);
    btrans_f2b<<<dim3(Cc  / 32, Cc / 32, 1), tb, 0, stream>>>(Wproj, WprojT, Cc, Cc);
    btrans_f2b<<<dim3(CM  / 32, Cc / 32, 1), tb, 0, stream>>>(W1,    W1T,    Cc, CM);
    btrans_f2b<<<dim3(Cc  / 32, CM / 32, 1), tb, 0, stream>>>(W2,    W2T,    CM, Cc);

    // qkv + attention, chunked over batches
    for (int c = 0; c < nq; ++c) {
        gemm_bt<0><<<dim3(768 / 128, Mq / 256), 512, 0, stream>>>(
            t0 + (size_t)c * Mq * Cc, WqkvT, bqkv, scr, Mq, 768, Cc, 0,
            nullptr, nullptr, nullptr, nullptr, nullptr, nullptr, nullptr, nullptr);
        attn_kernel<<<dim3(Bq * 8), 256, 0, stream>>>(scr, obuf + (size_t)c * Mq * Cc);
    }

    // t1 = RepBN1(t0 + obuf @ Wproj + bproj)
    gemm_bt<1><<<dim3(Cc / 128, M / 256), 512, 0, stream>>>(
        obuf, WprojT, bproj, t1b, M, Cc, Cc, 0,
        t0, g1, be1, rm1, rv1, alpha1, nullptr, nullptr);

    // FFN, chunked over rows
    for (int c = 0; c < nf; ++c) {
        gemm_bt<2><<<dim3(CM / 128, Mf / 256), 512, 0, stream>>>(
            t1b + (size_t)c * Mf * Cc, W1T, b1, scr, Mf, CM, Cc, c * Mf,
            nullptr, nullptr, nullptr, nullptr, nullptr, nullptr, saw, sab);
        gemm_bt<1><<<dim3(Cc / 128, Mf / 256), 512, 0, stream>>>(
            scr, W2T, b2, t2 + (size_t)c * Mf * Cc, Mf, Cc, CM, 0,
            t1b + (size_t)c * Mf * Cc, g2, be2, rm2, rv2, alpha2, nullptr, nullptr);
    }

    // t2 bf16 [B][N][C] -> out f32 [B][C][N]
    btrans_b2f<<<dim3((Cc + 31) / 32, (Np + 31) / 32, B), tb, 0, stream>>>(t2, out, Np, Cc);
}